// Round 1
// baseline (671.486 us; speedup 1.0000x reference)
//
#include <hip/hip_runtime.h>
#include <hip/hip_bf16.h>

#define NN 20000
#define NE 100000
#define EB 16
#define NBLK (NE / EB)

typedef __attribute__((ext_vector_type(8))) short bf16x8;
typedef __attribute__((ext_vector_type(4))) float f32x4;
typedef __attribute__((ext_vector_type(16))) float f32x16;

__device__ __forceinline__ unsigned short f2bf(float f) {
    unsigned u = __float_as_uint(f);
    u += 0x7fffu + ((u >> 16) & 1u);
    return (unsigned short)(u >> 16);
}

// ws layout: [0,131072) RbfT bf16 [pos(2048)][a(32)]; [131072,131076) int64-detect flag
__global__ void prep_rbf_kernel(const float* __restrict__ R, unsigned short* __restrict__ RbfT,
                                int* __restrict__ flag) {
    int idx = blockIdx.x * blockDim.x + threadIdx.x;
    if (idx == 0) *flag = 0;
    if (idx >= 2048 * 32) return;
    int pos = idx >> 5;
    int a = idx & 31;
    RbfT[idx] = f2bf(R[a * 2048 + pos]);
}

// Inspect first 200000 int32 words (safe under both dtypes). If edge_index is
// really int64 (values < 2^31), every odd word is a zero hi-word.
__global__ void detect_kernel(const unsigned* __restrict__ w, int* __restrict__ flag) {
    int k = blockIdx.x * blockDim.x + threadIdx.x;
    if (k < NE && w[2 * k + 1] != 0) atomicOr(flag, 1);
}

__global__ __launch_bounds__(512, 4) void sheaf_kernel(
    const float* __restrict__ x,
    const void* __restrict__ eidx_raw,
    const float* __restrict__ ea,
    const unsigned short* __restrict__ RbfT,
    const int* __restrict__ flag,
    float* __restrict__ out)
{
    __shared__ __align__(16) unsigned short F_lds[EB * 2048]; // [edge][side][32][32], rows XOR-swizzled
    __shared__ __align__(16) unsigned short dx_lds[8 * 1024]; // per-wave 32x32 bf16

    const int tid  = threadIdx.x;
    const int lane = tid & 63;
    const int wv   = tid >> 6;
    const int e0   = blockIdx.x * EB;
    const int use64 = (*flag == 0);

    // ---- Phase 1: F[16 edges][2048] = ea @ R via mfma 16x16x32 ----
    {
        const int arow = lane & 15;
        const int ab   = (lane >> 4) * 8;
        const float* eap = ea + (size_t)(e0 + arow) * 32 + ab;
        f32x4 a0 = *(const f32x4*)eap;
        f32x4 a1 = *(const f32x4*)(eap + 4);
        bf16x8 afrag;
#pragma unroll
        for (int j = 0; j < 4; ++j) { afrag[j] = (short)f2bf(a0[j]); afrag[4 + j] = (short)f2bf(a1[j]); }

        const int pcol  = lane & 15;
        const int ebase = (lane >> 4) * 4;
#pragma unroll
        for (int t = 0; t < 16; ++t) {
            const int pos = wv * 256 + t * 16 + pcol;
            bf16x8 bfrag = *(const bf16x8*)(RbfT + pos * 32 + ab);
            f32x4 acc = {0.f, 0.f, 0.f, 0.f};
            acc = __builtin_amdgcn_mfma_f32_16x16x32_bf16(afrag, bfrag, acc, 0, 0, 0);
            const int side = pos >> 10;
            const int ij   = pos & 1023;      // i*32 + j
            const int i    = ij >> 5;
            const int soff = side * 1024 + (ij ^ ((i & 7) << 3));
#pragma unroll
            for (int r = 0; r < 4; ++r)
                F_lds[(ebase + r) * 2048 + soff] = f2bf(acc[r]);
        }
    }
    __syncthreads();

    // ---- Phase 2: one wave per edge (2 sequential edges/wave) ----
    const int r31 = lane & 31;     // A-frag row / B,C-frag col
    const int hi  = lane >> 5;
    const int kb  = hi * 8;
    unsigned short* dxb = dx_lds + wv * 1024;

#pragma unroll 1
    for (int sub = 0; sub < 2; ++sub) {
        const int el = wv * 2 + sub;
        const int e  = e0 + el;
        int src, dst;
        if (use64) {
            const long long* e64 = (const long long*)eidx_raw;
            src = (int)e64[e]; dst = (int)e64[NE + e];
        } else {
            const int* e32 = (const int*)eidx_raw;
            src = e32[e]; dst = e32[NE + e];
        }
        if ((unsigned)src >= NN || (unsigned)dst >= NN) continue;

        // x fragments (B operands); x_right negated during convert
        const float* xl = x + (size_t)src * 1024 + r31;
        const float* xr = x + (size_t)dst * 1024 + r31;
        bf16x8 xlf0, xlf1, xrf0, xrf1;
#pragma unroll
        for (int j = 0; j < 8; ++j) {
            xlf0[j] = (short)f2bf(xl[(kb + j) * 32]);
            xlf1[j] = (short)f2bf(xl[(16 + kb + j) * 32]);
            xrf0[j] = (short)f2bf(-xr[(kb + j) * 32]);
            xrf1[j] = (short)f2bf(-xr[(16 + kb + j) * 32]);
        }

        const unsigned short* Fl = F_lds + el * 2048;
        const unsigned short* Fr = Fl + 1024;
        const int rbase = r31 * 32;
        const int rsw   = (r31 & 7) << 3;
        bf16x8 fl0 = *(const bf16x8*)(Fl + ((rbase + kb) ^ rsw));
        bf16x8 fl1 = *(const bf16x8*)(Fl + ((rbase + 16 + kb) ^ rsw));
        bf16x8 fr0 = *(const bf16x8*)(Fr + ((rbase + kb) ^ rsw));
        bf16x8 fr1 = *(const bf16x8*)(Fr + ((rbase + 16 + kb) ^ rsw));

        f32x16 dacc;
#pragma unroll
        for (int r = 0; r < 16; ++r) dacc[r] = 0.f;
        dacc = __builtin_amdgcn_mfma_f32_32x32x16_bf16(fl0, xlf0, dacc, 0, 0, 0);
        dacc = __builtin_amdgcn_mfma_f32_32x32x16_bf16(fl1, xlf1, dacc, 0, 0, 0);
        dacc = __builtin_amdgcn_mfma_f32_32x32x16_bf16(fr0, xrf0, dacc, 0, 0, 0);
        dacc = __builtin_amdgcn_mfma_f32_32x32x16_bf16(fr1, xrf1, dacc, 0, 0, 0);

        // dx -> LDS (bf16), then read back as B-fragment (same wave: DS ops in order)
#pragma unroll
        for (int r = 0; r < 16; ++r) {
            const int row = (r & 3) + 8 * (r >> 2) + 4 * hi;
            dxb[row * 32 + r31] = f2bf(dacc[r]);
        }
        bf16x8 dxf0, dxf1;
#pragma unroll
        for (int j = 0; j < 8; ++j) {
            dxf0[j] = (short)dxb[(kb + j) * 32 + r31];
            dxf1[j] = (short)dxb[(16 + kb + j) * 32 + r31];
        }

        // y_left = F_l^T dx
        bf16x8 flT0, flT1;
#pragma unroll
        for (int j = 0; j < 8; ++j) {
            const int k0 = kb + j, k1 = 16 + kb + j;
            flT0[j] = (short)Fl[(k0 * 32 + r31) ^ ((k0 & 7) << 3)];
            flT1[j] = (short)Fl[(k1 * 32 + r31) ^ ((k1 & 7) << 3)];
        }
        f32x16 yl;
#pragma unroll
        for (int r = 0; r < 16; ++r) yl[r] = 0.f;
        yl = __builtin_amdgcn_mfma_f32_32x32x16_bf16(flT0, dxf0, yl, 0, 0, 0);
        yl = __builtin_amdgcn_mfma_f32_32x32x16_bf16(flT1, dxf1, yl, 0, 0, 0);

        float* outs = out + (size_t)src * 1024 + r31;
#pragma unroll
        for (int r = 0; r < 16; ++r) {
            const int row = (r & 3) + 8 * (r >> 2) + 4 * hi;
            atomicAdd(outs + row * 32, yl[r]);
        }

        // y_right = F_r^T dx
        bf16x8 frT0, frT1;
#pragma unroll
        for (int j = 0; j < 8; ++j) {
            const int k0 = kb + j, k1 = 16 + kb + j;
            frT0[j] = (short)Fr[(k0 * 32 + r31) ^ ((k0 & 7) << 3)];
            frT1[j] = (short)Fr[(k1 * 32 + r31) ^ ((k1 & 7) << 3)];
        }
        f32x16 yr;
#pragma unroll
        for (int r = 0; r < 16; ++r) yr[r] = 0.f;
        yr = __builtin_amdgcn_mfma_f32_32x32x16_bf16(frT0, dxf0, yr, 0, 0, 0);
        yr = __builtin_amdgcn_mfma_f32_32x32x16_bf16(frT1, dxf1, yr, 0, 0, 0);

        float* outd = out + (size_t)dst * 1024 + r31;
#pragma unroll
        for (int r = 0; r < 16; ++r) {
            const int row = (r & 3) + 8 * (r >> 2) + 4 * hi;
            atomicAdd(outd + row * 32, -yr[r]);
        }
    }
}

extern "C" void kernel_launch(void* const* d_in, const int* in_sizes, int n_in,
                              void* d_out, int out_size, void* d_ws, size_t ws_size,
                              hipStream_t stream) {
    const float* x  = (const float*)d_in[0];
    const void* eidx = d_in[1];
    const float* ea = (const float*)d_in[2];
    const float* R  = (const float*)d_in[3];
    float* out = (float*)d_out;
    unsigned short* RbfT = (unsigned short*)d_ws;
    int* flag = (int*)((char*)d_ws + 131072);

    hipMemsetAsync(d_out, 0, (size_t)out_size * sizeof(float), stream);
    prep_rbf_kernel<<<257, 256, 0, stream>>>(R, RbfT, flag);
    detect_kernel<<<(NE + 255) / 256, 256, 0, stream>>>((const unsigned*)eidx, flag);
    sheaf_kernel<<<NBLK, 512, 0, stream>>>(x, eidx, ea, RbfT, flag, out);
}